// Round 7
// baseline (99.678 us; speedup 1.0000x reference)
//
#include <hip/hip_runtime.h>

// MoE experts: route -> gather(bf16) -> grouped GEMM1+silu -> grouped GEMM2 -> atomic combine
// GEMM K-loop: all staging via global_load_lds (A bf16 direct, W fp32 -> in-LDS transpose+convert),
// counted vmcnt across raw barriers (loads stay in flight), double-buffered LDS.
#define E_ 16
#define T_ 2048
#define H_ 1024
#define I_ 512
#define NPAIR 4096             // T*K token-expert pairs
#define BM 128
#define MAXTILE 48             // sum ceil(ne/BM) <= 32 + 16

typedef __bf16 bf16x8 __attribute__((ext_vector_type(8)));
typedef float  f32x4  __attribute__((ext_vector_type(4)));

static __device__ __forceinline__ unsigned short f2bf(float f) {
    __bf16 h = (__bf16)f;                       // RNE
    return __builtin_bit_cast(unsigned short, h);
}

static __device__ __forceinline__ uint4 pack8(const float* v) {
    union { unsigned short us[8]; uint4 u; } r;
    #pragma unroll
    for (int i = 0; i < 8; ++i) r.us[i] = f2bf(v[i]);
    return r.u;
}

// async global->LDS, 16B/lane; dest wave-uniform base + lane*16 (linear)
static __device__ __forceinline__ void gl_lds16(const void* g, void* l) {
    __builtin_amdgcn_global_load_lds(
        (const __attribute__((address_space(1))) unsigned int*)g,
        (__attribute__((address_space(3))) unsigned int*)l,
        16, 0, 0);
}

// ---------------- routing: stable counting sort + tile map -----------------
__global__ __launch_bounds__(256) void route_kernel(
    const float* __restrict__ tw, const int* __restrict__ ti,
    int* __restrict__ offs, int* __restrict__ tile_e, int* __restrict__ tile_r,
    int* __restrict__ pair_ts, float* __restrict__ pair_w)
{
    __shared__ unsigned short hist[256][E_];
    __shared__ int ebase[E_];
    const int tid = threadIdx.x;

    int e_loc[16];
    unsigned short h[E_];
    for (int e = 0; e < E_; ++e) h[e] = 0;
    for (int i = 0; i < 16; ++i) {
        int p = tid * 16 + i;
        int e = ti[p];
        e_loc[i] = e;
        h[e]++;
    }
    for (int e = 0; e < E_; ++e) hist[tid][e] = h[e];
    __syncthreads();

    if (tid < E_) {
        int e = tid, run = 0;
        for (int t = 0; t < 256; ++t) {
            unsigned short c = hist[t][e];
            hist[t][e] = (unsigned short)run;
            run += c;
        }
        ebase[e] = run;
    }
    __syncthreads();
    if (tid == 0) {
        int run = 0, nt = 0;
        for (int e = 0; e < E_; ++e) {
            int c = ebase[e];
            offs[e] = run; ebase[e] = run;
            for (int r = 0; r < c; r += BM) { tile_e[nt] = e; tile_r[nt] = r; ++nt; }
            run += c;
        }
        offs[E_] = run;
        for (; nt < MAXTILE; ++nt) tile_e[nt] = -1;
    }
    __syncthreads();

    int cur[E_];
    for (int e = 0; e < E_; ++e) cur[e] = ebase[e] + hist[tid][e];
    for (int i = 0; i < 16; ++i) {
        int p = tid * 16 + i;
        int e = e_loc[i];
        int pos = cur[e]++;
        pair_ts[pos] = p;          // t = p>>1
        pair_w[pos]  = tw[p];
    }
}

// ---------------- gather: Ag[q][:] = bf16(X[token(q)][:]) ------------------
__global__ __launch_bounds__(256) void gather_kernel(
    const float* __restrict__ X, const int* __restrict__ pair_ts,
    unsigned short* __restrict__ Ag)
{
    const int q = blockIdx.x;
    const int t = pair_ts[q] >> 1;
    const int c = threadIdx.x * 4;
    const float4 x = *(const float4*)&X[(size_t)t * H_ + c];
    ushort4 b; b.x = f2bf(x.x); b.y = f2bf(x.y); b.z = f2bf(x.z); b.w = f2bf(x.w);
    *(ushort4*)&Ag[(size_t)q * H_ + c] = b;
}

// ---------------- shared GEMM machinery ------------------------------------
// 4 waves (2x2), wave tile 64x32, block 128x64, BK=64.
// XOR-swizzled bf16 LDS: 16B granule g of row r holds source granule g^(r&7).
#define MFMA_TILE(AS, BS)                                                              \
    _Pragma("unroll")                                                                  \
    for (int kkj = 0; kkj < 2; ++kkj) {                                                \
        const int j0 = kkj * 4;                                                        \
        bf16x8 af[4], bfr[2];                                                          \
        _Pragma("unroll")                                                              \
        for (int m = 0; m < 4; ++m)                                                    \
            af[m] = *(const bf16x8*)&AS[wm * 64 + m * 16 + lrow][((j0 + lk) ^ (lrow & 7)) * 8]; \
        _Pragma("unroll")                                                              \
        for (int n = 0; n < 2; ++n)                                                    \
            bfr[n] = *(const bf16x8*)&BS[wn * 32 + n * 16 + lrow][((j0 + lk) ^ (lrow & 7)) * 8]; \
        _Pragma("unroll")                                                              \
        for (int m = 0; m < 4; ++m)                                                    \
            _Pragma("unroll")                                                          \
            for (int n = 0; n < 2; ++n)                                                \
                acc[m][n] = __builtin_amdgcn_mfma_f32_16x16x32_bf16(af[m], bfr[n], acc[m][n], 0, 0, 0); \
    }

// A tile stage: 4 x gl_lds16 per wave (8 rows each), pre-swizzled source granules.
#define STAGE_A(BUF, KB)                                                               \
    _Pragma("unroll")                                                                  \
    for (int i = 0; i < 4; ++i) gl_lds16(asrc[i] + (KB), &As[BUF][w * 32 + i * 8][0]);

// W tile stage (fp32, linear): 4 x gl_lds16 per wave (4 k-rows each). Wave w owns
// k-rows w*16..w*16+15 of Wf. Per-lane src = wsrc + (KB + w*16 + i*4 + kloc)*WSTRIDE.
#define STAGE_W(BUF, KB, WSTRIDE)                                                      \
    _Pragma("unroll")                                                                  \
    for (int i = 0; i < 4; ++i)                                                        \
        gl_lds16(wsrc + (size_t)((KB) + w * 16 + i * 4 + kloc) * (WSTRIDE),            \
                 &Wf[BUF][w * 16 + i * 4][0]);

// In-LDS transpose+convert: wave w reads its own 16 k-rows of Wf[CUR] (lane = col n,
// conflict-free 256B rows), writes bf16 k-strips into swizzled Bs[NXT] row trow.
#define TRANSPOSE_W(CUR, NXT)                                                          \
    {                                                                                  \
        float tv[16];                                                                  \
        _Pragma("unroll")                                                              \
        for (int i = 0; i < 16; ++i) tv[i] = Wf[CUR][w * 16 + i][lane];                \
        *(uint4*)&Bs[NXT][trow][tg0 * 8] = pack8(&tv[0]);                              \
        *(uint4*)&Bs[NXT][trow][tg1 * 8] = pack8(&tv[8]);                              \
    }

// Pipelined K-loop: issue next tiles, counted vmcnt (loads cross barriers), then
// transpose (for j+1) interleaved with MFMA (on j).
#define K_PIPE(NT, WSTRIDE)                                                            \
    STAGE_A(0, 0)                                                                      \
    STAGE_W(1, 0, WSTRIDE)                                                             \
    asm volatile("s_waitcnt vmcnt(0) lgkmcnt(0)" ::: "memory");                        \
    asm volatile("s_barrier" ::: "memory");                                            \
    TRANSPOSE_W(1, 0)                                                                  \
    STAGE_W(0, 64, WSTRIDE)                                                            \
    asm volatile("s_waitcnt lgkmcnt(0)" ::: "memory");                                 \
    asm volatile("s_barrier" ::: "memory");                                            \
    _Pragma("unroll")                                                                  \
    for (int j = 0; j < (NT); ++j) {                                                   \
        const int cur = j & 1, nxt = cur ^ 1;                                          \
        if (j + 1 < (NT)) STAGE_A(nxt, (j + 1) * 64)                                   \
        if (j + 2 < (NT)) STAGE_W(nxt, (j + 2) * 64, WSTRIDE)                          \
        if (j + 2 < (NT)) {                                                            \
            asm volatile("s_waitcnt vmcnt(8)" ::: "memory");                           \
        } else if (j + 1 < (NT)) {                                                     \
            asm volatile("s_waitcnt vmcnt(4)" ::: "memory");                           \
        } else {                                                                       \
            asm volatile("s_waitcnt vmcnt(0)" ::: "memory");                           \
        }                                                                              \
        asm volatile("s_barrier" ::: "memory");                                        \
        if (j + 1 < (NT)) TRANSPOSE_W(cur, nxt)                                        \
        __builtin_amdgcn_s_setprio(1);                                                 \
        MFMA_TILE(As[cur], Bs[cur])                                                    \
        __builtin_amdgcn_s_setprio(0);                                                 \
        if (j + 1 < (NT)) {                                                            \
            asm volatile("s_waitcnt lgkmcnt(0)" ::: "memory");                         \
            asm volatile("s_barrier" ::: "memory");                                    \
        }                                                                              \
    }

// ---------------- grouped GEMM1 + fused silu-gate --------------------------
// BM=128, BN=64 (32 gate + 32 up), K=H_=1024 (16 steps). Dense tile-mapped grid.
__global__ __launch_bounds__(256, 2) void gemm1_kernel(
    const unsigned short* __restrict__ Ag, const float* __restrict__ W1,
    const int* __restrict__ offs, const int* __restrict__ tile_e,
    const int* __restrict__ tile_r, unsigned short* __restrict__ act)
{
    const int e = tile_e[blockIdx.y];
    if (e < 0) return;
    const int rbeg = offs[e], rend = offs[e + 1];
    const int ne   = rend - rbeg;
    const int row0 = tile_r[blockIdx.y];
    const int c0 = blockIdx.x * 32;          // act cols; gate cols c0.., up cols I_+c0..

    __shared__ unsigned short As[2][128][64];   // 32 KB
    __shared__ float          Wf[2][64][64];    // 32 KB (fp32 staging)
    __shared__ unsigned short Bs[2][64][64];    // 16 KB

    const int tid  = threadIdx.x;
    const int lane = tid & 63;
    const int w    = tid >> 6;        // 0..3
    const int wm   = w >> 1, wn = w & 1;
    const int lrow = lane & 15;
    const int lk   = lane >> 4;

    const float* __restrict__ W1e = W1 + (size_t)e * (H_ * 2 * I_);

    // A sources: wave w stages rows [w*32, w*32+32), pre-swizzled granule
    const int r8 = lane >> 3, gr = lane & 7;
    const unsigned short* asrc[4];
    #pragma unroll
    for (int i = 0; i < 4; ++i) {
        int q = rbeg + row0 + w * 32 + i * 8 + r8;
        if (q > rend - 1) q = rend - 1;
        asrc[i] = Ag + (size_t)q * H_ + (gr ^ r8) * 8;
    }

    // W source: Wf col n = nf..nf+3 maps n<32 -> gate col c0+n, n>=32 -> up col I_+c0+(n-32)
    const int nf   = (lane & 15) * 4;
    const int kloc = lane >> 4;       // 0..3
    const float* __restrict__ wsrc =
        W1e + ((nf < 32) ? (c0 + nf) : (I_ + c0 + (nf - 32)));

    // transpose: lane = Wf col n; Bs row = quarter-swapped (frag/epilogue mapping)
    {   // nothing
    }
    const int tq   = lane >> 4;
    const int tqr  = ((tq & 1) << 1) | (tq >> 1);   // 2-bit reverse: 1<->2
    const int trow = tqr * 16 + (lane & 15);
    const int tg0  = (2 * w)     ^ (trow & 7);
    const int tg1  = (2 * w + 1) ^ (trow & 7);

    f32x4 acc[4][2];
    #pragma unroll
    for (int m = 0; m < 4; ++m)
        #pragma unroll
        for (int n = 0; n < 2; ++n)
            acc[m][n] = f32x4{0.f, 0.f, 0.f, 0.f};

    K_PIPE(16, 2 * I_)

    // epilogue: frag 0 = gate, frag 1 = up for act col c0 + wn*16 + lrow
    for (int m = 0; m < 4; ++m) {
        #pragma unroll
        for (int reg = 0; reg < 4; ++reg) {
            int rloc = wm * 64 + m * 16 + lk * 4 + reg;
            if (row0 + rloc < ne) {
                int q = rbeg + row0 + rloc;
                float g = acc[m][0][reg], u = acc[m][1][reg];
                float a = g / (1.f + __expf(-g)) * u;
                act[(size_t)q * I_ + c0 + wn * 16 + lrow] = f2bf(a);
            }
        }
    }
}

// ---------------- grouped GEMM2 + weighted atomic combine ------------------
// BM=128, BN=64, K=I_=512 (8 steps). Dense tile-mapped grid.
__global__ __launch_bounds__(256, 2) void gemm2_kernel(
    const unsigned short* __restrict__ Agact, const float* __restrict__ W2,
    const int* __restrict__ offs, const int* __restrict__ tile_e,
    const int* __restrict__ tile_r, const int* __restrict__ pair_ts,
    const float* __restrict__ pair_w, float* __restrict__ out)
{
    const int e = tile_e[blockIdx.y];
    if (e < 0) return;
    const int rbeg = offs[e], rend = offs[e + 1];
    const int ne   = rend - rbeg;
    const int row0 = tile_r[blockIdx.y];
    const int c0 = blockIdx.x * 64;

    __shared__ unsigned short As[2][128][64];
    __shared__ float          Wf[2][64][64];
    __shared__ unsigned short Bs[2][64][64];

    const int tid  = threadIdx.x;
    const int lane = tid & 63;
    const int w    = tid >> 6;
    const int wm   = w >> 1, wn = w & 1;
    const int lrow = lane & 15;
    const int lk   = lane >> 4;

    const float* __restrict__ W2e = W2 + (size_t)e * (I_ * H_);

    const int r8 = lane >> 3, gr = lane & 7;
    const unsigned short* asrc[4];
    #pragma unroll
    for (int i = 0; i < 4; ++i) {
        int q = rbeg + row0 + w * 32 + i * 8 + r8;
        if (q > rend - 1) q = rend - 1;
        asrc[i] = Agact + (size_t)q * I_ + (gr ^ r8) * 8;
    }

    const int nf   = (lane & 15) * 4;
    const int kloc = lane >> 4;
    const float* __restrict__ wsrc = W2e + c0 + nf;

    const int trow = lane;                          // identity col map
    const int tg0  = (2 * w)     ^ (trow & 7);
    const int tg1  = (2 * w + 1) ^ (trow & 7);

    f32x4 acc[4][2];
    #pragma unroll
    for (int m = 0; m < 4; ++m)
        #pragma unroll
        for (int n = 0; n < 2; ++n)
            acc[m][n] = f32x4{0.f, 0.f, 0.f, 0.f};

    K_PIPE(8, H_)

    for (int m = 0; m < 4; ++m) {
        #pragma unroll
        for (int reg = 0; reg < 4; ++reg) {
            int rloc = wm * 64 + m * 16 + lk * 4 + reg;
            if (row0 + rloc < ne) {
                int q   = rbeg + row0 + rloc;
                int t   = pair_ts[q] >> 1;
                float wt = pair_w[q];
                #pragma unroll
                for (int n = 0; n < 2; ++n) {
                    int cg = c0 + wn * 32 + n * 16 + lrow;
                    atomicAdd(&out[(size_t)t * H_ + cg], wt * acc[m][n][reg]);
                }
            }
        }
    }
}

extern "C" void kernel_launch(void* const* d_in, const int* in_sizes, int n_in,
                              void* d_out, int out_size, void* d_ws, size_t ws_size,
                              hipStream_t stream)
{
    const float* X  = (const float*)d_in[0];   // [T,H]
    const float* tw = (const float*)d_in[1];   // [T,K]
    const int*   ti = (const int*)d_in[2];     // [T,K]
    const float* W1 = (const float*)d_in[3];   // [E,H,2I]
    const float* W2 = (const float*)d_in[4];   // [E,I,H]
    float* out = (float*)d_out;                // [T,H] fp32

    char* ws = (char*)d_ws;
    int*   offs    = (int*)(ws);               // 17 ints
    int*   tile_e  = (int*)(ws + 128);         // MAXTILE ints
    int*   tile_r  = (int*)(ws + 128 + MAXTILE * 4);
    int*   pair_ts = (int*)(ws + 1024);
    float* pair_w  = (float*)(ws + 1024 + NPAIR * 4);
    unsigned short* Ag  = (unsigned short*)(ws + (1u << 16));                          // 8 MiB
    unsigned short* act = (unsigned short*)(ws + (1u << 16) + (size_t)NPAIR * H_ * 2); // 4 MiB

    hipMemsetAsync(d_out, 0, (size_t)out_size * sizeof(float), stream);

    route_kernel<<<1, 256, 0, stream>>>(tw, ti, offs, tile_e, tile_r, pair_ts, pair_w);

    gather_kernel<<<NPAIR, 256, 0, stream>>>(X, pair_ts, Ag);

    gemm1_kernel<<<dim3(I_ / 32, MAXTILE), 256, 0, stream>>>(Ag, W1, offs, tile_e, tile_r, act);

    gemm2_kernel<<<dim3(H_ / 64, MAXTILE), 256, 0, stream>>>(act, W2, offs, tile_e, tile_r, pair_ts, pair_w, out);
}

// Round 8
// 98.764 us; speedup vs baseline: 1.0093x; 1.0093x over previous
//
#include <hip/hip_runtime.h>

// MoE experts: route -> gather(bf16) -> grouped GEMM1+silu -> grouped GEMM2 -> atomic combine
// GEMM K-loop: distance-2 never-drain pipeline. Per iter: issue tile j+2 (A via
// global_load_lds, B via 16 reg dwords), MFMA tile j, vmcnt(20) retires tile j+1,
// pack B j+1 -> LDS, lgkmcnt+raw barrier. vmcnt never drains below 20 in steady state.
#define E_ 16
#define T_ 2048
#define H_ 1024
#define I_ 512
#define NPAIR 4096             // T*K token-expert pairs
#define BM 128
#define MAXTILE 48             // sum ceil(ne/BM) <= 32 + 16

typedef __bf16 bf16x8 __attribute__((ext_vector_type(8)));
typedef float  f32x4  __attribute__((ext_vector_type(4)));

static __device__ __forceinline__ unsigned short f2bf(float f) {
    __bf16 h = (__bf16)f;                       // RNE
    return __builtin_bit_cast(unsigned short, h);
}

static __device__ __forceinline__ uint4 pack8(const float* v) {
    union { unsigned short us[8]; uint4 u; } r;
    #pragma unroll
    for (int i = 0; i < 8; ++i) r.us[i] = f2bf(v[i]);
    return r.u;
}

// async global->LDS, 16B/lane; dest wave-uniform base + lane*16 (linear)
static __device__ __forceinline__ void gl_lds16(const void* g, void* l) {
    __builtin_amdgcn_global_load_lds(
        (const __attribute__((address_space(1))) unsigned int*)g,
        (__attribute__((address_space(3))) unsigned int*)l,
        16, 0, 0);
}

// ---------------- routing: stable counting sort + tile map -----------------
__global__ __launch_bounds__(256) void route_kernel(
    const float* __restrict__ tw, const int* __restrict__ ti,
    int* __restrict__ offs, int* __restrict__ tile_e, int* __restrict__ tile_r,
    int* __restrict__ pair_ts, float* __restrict__ pair_w)
{
    __shared__ unsigned short hist[256][E_];
    __shared__ int ebase[E_];
    const int tid = threadIdx.x;

    int e_loc[16];
    unsigned short h[E_];
    for (int e = 0; e < E_; ++e) h[e] = 0;
    for (int i = 0; i < 16; ++i) {
        int p = tid * 16 + i;
        int e = ti[p];
        e_loc[i] = e;
        h[e]++;
    }
    for (int e = 0; e < E_; ++e) hist[tid][e] = h[e];
    __syncthreads();

    if (tid < E_) {
        int e = tid, run = 0;
        for (int t = 0; t < 256; ++t) {
            unsigned short c = hist[t][e];
            hist[t][e] = (unsigned short)run;
            run += c;
        }
        ebase[e] = run;
    }
    __syncthreads();
    if (tid == 0) {
        int run = 0, nt = 0;
        for (int e = 0; e < E_; ++e) {
            int c = ebase[e];
            offs[e] = run; ebase[e] = run;
            for (int r = 0; r < c; r += BM) { tile_e[nt] = e; tile_r[nt] = r; ++nt; }
            run += c;
        }
        offs[E_] = run;
        for (; nt < MAXTILE; ++nt) tile_e[nt] = -1;
    }
    __syncthreads();

    int cur[E_];
    for (int e = 0; e < E_; ++e) cur[e] = ebase[e] + hist[tid][e];
    for (int i = 0; i < 16; ++i) {
        int p = tid * 16 + i;
        int e = e_loc[i];
        int pos = cur[e]++;
        pair_ts[pos] = p;          // t = p>>1
        pair_w[pos]  = tw[p];
    }
}

// ---------------- gather: Ag[q][:] = bf16(X[token(q)][:]) ------------------
__global__ __launch_bounds__(256) void gather_kernel(
    const float* __restrict__ X, const int* __restrict__ pair_ts,
    unsigned short* __restrict__ Ag)
{
    const int q = blockIdx.x;
    const int t = pair_ts[q] >> 1;
    const int c = threadIdx.x * 4;
    const float4 x = *(const float4*)&X[(size_t)t * H_ + c];
    ushort4 b; b.x = f2bf(x.x); b.y = f2bf(x.y); b.z = f2bf(x.z); b.w = f2bf(x.w);
    *(ushort4*)&Ag[(size_t)q * H_ + c] = b;
}

// ---------------- shared GEMM machinery ------------------------------------
// 4 waves (2x2), wave tile 64x32, block 128x64, BK=64.
// XOR-swizzled bf16 LDS: 16B granule g of row r holds source granule g^(r&7).
#define MFMA_TILE(AS, BS)                                                              \
    _Pragma("unroll")                                                                  \
    for (int kkj = 0; kkj < 2; ++kkj) {                                                \
        const int j0 = kkj * 4;                                                        \
        bf16x8 af[4], bfr[2];                                                          \
        _Pragma("unroll")                                                              \
        for (int m = 0; m < 4; ++m)                                                    \
            af[m] = *(const bf16x8*)&AS[wm * 64 + m * 16 + lrow][((j0 + lk) ^ (lrow & 7)) * 8]; \
        _Pragma("unroll")                                                              \
        for (int n = 0; n < 2; ++n)                                                    \
            bfr[n] = *(const bf16x8*)&BS[wn * 32 + n * 16 + lrow][((j0 + lk) ^ (lrow & 7)) * 8]; \
        _Pragma("unroll")                                                              \
        for (int m = 0; m < 4; ++m)                                                    \
            _Pragma("unroll")                                                          \
            for (int n = 0; n < 2; ++n)                                                \
                acc[m][n] = __builtin_amdgcn_mfma_f32_16x16x32_bf16(af[m], bfr[n], acc[m][n], 0, 0, 0); \
    }

// A tile stage: 4 x gl_lds16 per wave (8 rows each), pre-swizzled source granules.
#define STAGE_A(BUF, KB)                                                               \
    _Pragma("unroll")                                                                  \
    for (int i = 0; i < 4; ++i) gl_lds16(asrc[i] + (KB), &As[BUF][w * 32 + i * 8][0]);

// B tile reg-issue: thread (w, bn) loads 16 k-values (k = KB + w*16 + i) of col bn.
#define ISSUE_BV(BV, KB, BSTRIDE)                                                      \
    _Pragma("unroll")                                                                  \
    for (int i = 0; i < 16; ++i)                                                       \
        BV[i] = bsrc[(size_t)((KB) + w * 16 + i) * (BSTRIDE)];

// B pack: convert + write the two swizzled 16B granules (2w, 2w+1) of row bn.
#define PACK_B(BS, BV)                                                                 \
    *(uint4*)&BS[bn][bg0] = pack8(&(BV)[0]);                                           \
    *(uint4*)&BS[bn][bg1] = pack8(&(BV)[8]);

// Distance-2 never-drain K-loop. Per wave per iter: 4 gl_lds + 16 dword loads issued;
// vmcnt(20) leaves exactly the newest batch (tile j+2) in flight and retires tile j+1
// (A before bv in issue order => counted retire covers both). Raw barriers only.
#define K_PIPE(NT, BSTRIDE)                                                            \
    float bvA[16], bvB[16], bvC[16];                                                   \
    STAGE_A(0, 0)                                                                      \
    ISSUE_BV(bvA, 0, BSTRIDE)                                                          \
    STAGE_A(1, 64)                                                                     \
    ISSUE_BV(bvB, 64, BSTRIDE)                                                         \
    asm volatile("s_waitcnt vmcnt(20)" ::: "memory");                                  \
    PACK_B(Bs[0], bvA)                                                                 \
    asm volatile("s_waitcnt lgkmcnt(0)" ::: "memory");                                 \
    asm volatile("s_barrier" ::: "memory");                                            \
    _Pragma("unroll")                                                                  \
    for (int j = 0; j < (NT); ++j) {                                                   \
        if (j + 2 < (NT)) {                                                            \
            STAGE_A((j + 2) % 3, (j + 2) * 64)                                         \
            if (((j + 2) % 3) == 0) { ISSUE_BV(bvA, (j + 2) * 64, BSTRIDE) }           \
            if (((j + 2) % 3) == 1) { ISSUE_BV(bvB, (j + 2) * 64, BSTRIDE) }           \
            if (((j + 2) % 3) == 2) { ISSUE_BV(bvC, (j + 2) * 64, BSTRIDE) }           \
        }                                                                              \
        __builtin_amdgcn_sched_barrier(0);                                             \
        __builtin_amdgcn_s_setprio(1);                                                 \
        MFMA_TILE(As[j % 3], Bs[j & 1])                                                \
        __builtin_amdgcn_s_setprio(0);                                                 \
        __builtin_amdgcn_sched_barrier(0);                                             \
        if (j + 1 < (NT)) {                                                            \
            if (j + 2 < (NT)) {                                                        \
                asm volatile("s_waitcnt vmcnt(20)" ::: "memory");                      \
            } else {                                                                   \
                asm volatile("s_waitcnt vmcnt(0)" ::: "memory");                       \
            }                                                                          \
            if (((j + 1) % 3) == 0) { PACK_B(Bs[(j + 1) & 1], bvA) }                   \
            if (((j + 1) % 3) == 1) { PACK_B(Bs[(j + 1) & 1], bvB) }                   \
            if (((j + 1) % 3) == 2) { PACK_B(Bs[(j + 1) & 1], bvC) }                   \
            asm volatile("s_waitcnt lgkmcnt(0)" ::: "memory");                         \
            asm volatile("s_barrier" ::: "memory");                                    \
        }                                                                              \
    }

// ---------------- grouped GEMM1 + fused silu-gate --------------------------
// BM=128, BN=64 (32 gate + 32 up), K=H_=1024 (16 steps). Dense tile-mapped grid.
__global__ __launch_bounds__(256, 2) void gemm1_kernel(
    const unsigned short* __restrict__ Ag, const float* __restrict__ W1,
    const int* __restrict__ offs, const int* __restrict__ tile_e,
    const int* __restrict__ tile_r, unsigned short* __restrict__ act)
{
    const int e = tile_e[blockIdx.y];
    if (e < 0) return;
    const int rbeg = offs[e], rend = offs[e + 1];
    const int ne   = rend - rbeg;
    const int row0 = tile_r[blockIdx.y];
    const int c0 = blockIdx.x * 32;          // act cols; gate cols c0.., up cols I_+c0..

    __shared__ unsigned short As[3][128][64];   // 48 KB
    __shared__ unsigned short Bs[2][64][64];    // 16 KB

    const int tid  = threadIdx.x;
    const int lane = tid & 63;
    const int w    = tid >> 6;        // 0..3
    const int wm   = w >> 1, wn = w & 1;
    const int lrow = lane & 15;
    const int lk   = lane >> 4;

    const float* __restrict__ W1e = W1 + (size_t)e * (H_ * 2 * I_);

    // A sources: wave w stages rows [w*32, w*32+32), pre-swizzled granule
    const int r8 = lane >> 3, gr = lane & 7;
    const unsigned short* asrc[4];
    #pragma unroll
    for (int i = 0; i < 4; ++i) {
        int q = rbeg + row0 + w * 32 + i * 8 + r8;
        if (q > rend - 1) q = rend - 1;
        asrc[i] = Ag + (size_t)q * H_ + (gr ^ r8) * 8;
    }

    // B: Bs row bn -> global col: half=(bn>>4)&1 (0 gate,1 up), grp=bn>>5, sub=bn&15
    const int bn   = lane;
    const int bcol = ((bn >> 4) & 1) * I_ + c0 + (bn >> 5) * 16 + (bn & 15);
    const float* __restrict__ bsrc = W1e + bcol;
    const int bg0 = ((2 * w)     ^ (bn & 7)) * 8;
    const int bg1 = ((2 * w + 1) ^ (bn & 7)) * 8;

    f32x4 acc[4][2];
    #pragma unroll
    for (int m = 0; m < 4; ++m)
        #pragma unroll
        for (int n = 0; n < 2; ++n)
            acc[m][n] = f32x4{0.f, 0.f, 0.f, 0.f};

    K_PIPE(16, 2 * I_)

    // epilogue: frag 0 = gate, frag 1 = up for act col c0 + wn*16 + lrow
    for (int m = 0; m < 4; ++m) {
        #pragma unroll
        for (int reg = 0; reg < 4; ++reg) {
            int rloc = wm * 64 + m * 16 + lk * 4 + reg;
            if (row0 + rloc < ne) {
                int q = rbeg + row0 + rloc;
                float g = acc[m][0][reg], u = acc[m][1][reg];
                float a = g / (1.f + __expf(-g)) * u;
                act[(size_t)q * I_ + c0 + wn * 16 + lrow] = f2bf(a);
            }
        }
    }
}

// ---------------- grouped GEMM2 + weighted atomic combine ------------------
// BM=128, BN=64, K=I_=512 (8 steps). Dense tile-mapped grid.
__global__ __launch_bounds__(256, 2) void gemm2_kernel(
    const unsigned short* __restrict__ Agact, const float* __restrict__ W2,
    const int* __restrict__ offs, const int* __restrict__ tile_e,
    const int* __restrict__ tile_r, const int* __restrict__ pair_ts,
    const float* __restrict__ pair_w, float* __restrict__ out)
{
    const int e = tile_e[blockIdx.y];
    if (e < 0) return;
    const int rbeg = offs[e], rend = offs[e + 1];
    const int ne   = rend - rbeg;
    const int row0 = tile_r[blockIdx.y];
    const int c0 = blockIdx.x * 64;

    __shared__ unsigned short As[3][128][64];
    __shared__ unsigned short Bs[2][64][64];

    const int tid  = threadIdx.x;
    const int lane = tid & 63;
    const int w    = tid >> 6;
    const int wm   = w >> 1, wn = w & 1;
    const int lrow = lane & 15;
    const int lk   = lane >> 4;

    const float* __restrict__ W2e = W2 + (size_t)e * (I_ * H_);

    const int r8 = lane >> 3, gr = lane & 7;
    const unsigned short* asrc[4];
    #pragma unroll
    for (int i = 0; i < 4; ++i) {
        int q = rbeg + row0 + w * 32 + i * 8 + r8;
        if (q > rend - 1) q = rend - 1;
        asrc[i] = Agact + (size_t)q * I_ + (gr ^ r8) * 8;
    }

    const int bn = lane;
    const float* __restrict__ bsrc = W2e + c0 + bn;
    const int bg0 = ((2 * w)     ^ (bn & 7)) * 8;
    const int bg1 = ((2 * w + 1) ^ (bn & 7)) * 8;

    f32x4 acc[4][2];
    #pragma unroll
    for (int m = 0; m < 4; ++m)
        #pragma unroll
        for (int n = 0; n < 2; ++n)
            acc[m][n] = f32x4{0.f, 0.f, 0.f, 0.f};

    K_PIPE(8, H_)

    for (int m = 0; m < 4; ++m) {
        #pragma unroll
        for (int reg = 0; reg < 4; ++reg) {
            int rloc = wm * 64 + m * 16 + lk * 4 + reg;
            if (row0 + rloc < ne) {
                int q   = rbeg + row0 + rloc;
                int t   = pair_ts[q] >> 1;
                float wt = pair_w[q];
                #pragma unroll
                for (int n = 0; n < 2; ++n) {
                    int cg = c0 + wn * 32 + n * 16 + lrow;
                    atomicAdd(&out[(size_t)t * H_ + cg], wt * acc[m][n][reg]);
                }
            }
        }
    }
}

extern "C" void kernel_launch(void* const* d_in, const int* in_sizes, int n_in,
                              void* d_out, int out_size, void* d_ws, size_t ws_size,
                              hipStream_t stream)
{
    const float* X  = (const float*)d_in[0];   // [T,H]
    const float* tw = (const float*)d_in[1];   // [T,K]
    const int*   ti = (const int*)d_in[2];     // [T,K]
    const float* W1 = (const float*)d_in[3];   // [E,H,2I]
    const float* W2 = (const float*)d_in[4];   // [E,I,H]
    float* out = (float*)d_out;                // [T,H] fp32

    char* ws = (char*)d_ws;
    int*   offs    = (int*)(ws);               // 17 ints
    int*   tile_e  = (int*)(ws + 128);         // MAXTILE ints
    int*   tile_r  = (int*)(ws + 128 + MAXTILE * 4);
    int*   pair_ts = (int*)(ws + 1024);
    float* pair_w  = (float*)(ws + 1024 + NPAIR * 4);
    unsigned short* Ag  = (unsigned short*)(ws + (1u << 16));                          // 8 MiB
    unsigned short* act = (unsigned short*)(ws + (1u << 16) + (size_t)NPAIR * H_ * 2); // 4 MiB

    hipMemsetAsync(d_out, 0, (size_t)out_size * sizeof(float), stream);

    route_kernel<<<1, 256, 0, stream>>>(tw, ti, offs, tile_e, tile_r, pair_ts, pair_w);

    gather_kernel<<<NPAIR, 256, 0, stream>>>(X, pair_ts, Ag);

    gemm1_kernel<<<dim3(I_ / 32, MAXTILE), 256, 0, stream>>>(Ag, W1, offs, tile_e, tile_r, act);

    gemm2_kernel<<<dim3(H_ / 64, MAXTILE), 256, 0, stream>>>(act, W2, offs, tile_e, tile_r, pair_ts, pair_w, out);
}

// Round 9
// 93.480 us; speedup vs baseline: 1.0663x; 1.0565x over previous
//
#include <hip/hip_runtime.h>

// MoE experts: route -> gather(bf16) -> W repack (fp32 strided -> bf16 packets) ->
// grouped GEMM1+silu -> grouped GEMM2 -> atomic combine.
// Key change: GEMMs never touch strided fp32. A one-time transform reads W
// contiguously and emits 8KB bf16 "packets" that ARE the swizzled LDS image;
// GEMM staging is then pure global_load_lds (6 per wave per K-step).
#define E_ 16
#define T_ 2048
#define H_ 1024
#define I_ 512
#define NPAIR 4096             // T*K token-expert pairs
#define BM 128
#define MAXTILE 48             // sum ceil(ne/BM) <= 32 + 16

typedef __bf16 bf16x8 __attribute__((ext_vector_type(8)));
typedef float  f32x4  __attribute__((ext_vector_type(4)));

static __device__ __forceinline__ unsigned short f2bf(float f) {
    __bf16 h = (__bf16)f;                       // RNE
    return __builtin_bit_cast(unsigned short, h);
}

static __device__ __forceinline__ uint4 pack8(const float* v) {
    union { unsigned short us[8]; uint4 u; } r;
    #pragma unroll
    for (int i = 0; i < 8; ++i) r.us[i] = f2bf(v[i]);
    return r.u;
}

// async global->LDS, 16B/lane; dest wave-uniform base + lane*16 (linear);
// source address is per-lane.
static __device__ __forceinline__ void gl_lds16(const void* g, void* l) {
    __builtin_amdgcn_global_load_lds(
        (const __attribute__((address_space(1))) unsigned int*)g,
        (__attribute__((address_space(3))) unsigned int*)l,
        16, 0, 0);
}

// ---------------- routing: stable counting sort + tile map -----------------
__global__ __launch_bounds__(256) void route_kernel(
    const float* __restrict__ tw, const int* __restrict__ ti,
    int* __restrict__ offs, int* __restrict__ tile_e, int* __restrict__ tile_r,
    int* __restrict__ pair_ts, float* __restrict__ pair_w)
{
    __shared__ unsigned short hist[256][E_];
    __shared__ int ebase[E_];
    const int tid = threadIdx.x;

    int e_loc[16];
    unsigned short h[E_];
    for (int e = 0; e < E_; ++e) h[e] = 0;
    for (int i = 0; i < 16; ++i) {
        int p = tid * 16 + i;
        int e = ti[p];
        e_loc[i] = e;
        h[e]++;
    }
    for (int e = 0; e < E_; ++e) hist[tid][e] = h[e];
    __syncthreads();

    if (tid < E_) {
        int e = tid, run = 0;
        for (int t = 0; t < 256; ++t) {
            unsigned short c = hist[t][e];
            hist[t][e] = (unsigned short)run;
            run += c;
        }
        ebase[e] = run;
    }
    __syncthreads();
    if (tid == 0) {
        int run = 0, nt = 0;
        for (int e = 0; e < E_; ++e) {
            int c = ebase[e];
            offs[e] = run; ebase[e] = run;
            for (int r = 0; r < c; r += BM) { tile_e[nt] = e; tile_r[nt] = r; ++nt; }
            run += c;
        }
        offs[E_] = run;
        for (; nt < MAXTILE; ++nt) tile_e[nt] = -1;
    }
    __syncthreads();

    int cur[E_];
    for (int e = 0; e < E_; ++e) cur[e] = ebase[e] + hist[tid][e];
    for (int i = 0; i < 16; ++i) {
        int p = tid * 16 + i;
        int e = e_loc[i];
        int pos = cur[e]++;
        pair_ts[pos] = p;          // t = p>>1
        pair_w[pos]  = tw[p];
    }
}

// ---------------- gather: Ag[q][:] = bf16(X[token(q)][:]) ------------------
__global__ __launch_bounds__(256) void gather_kernel(
    const float* __restrict__ X, const int* __restrict__ pair_ts,
    unsigned short* __restrict__ Ag)
{
    const int q = blockIdx.x;
    const int t = pair_ts[q] >> 1;
    const int c = threadIdx.x * 4;
    const float4 x = *(const float4*)&X[(size_t)t * H_ + c];
    ushort4 b; b.x = f2bf(x.x); b.y = f2bf(x.y); b.z = f2bf(x.z); b.w = f2bf(x.w);
    *(ushort4*)&Ag[(size_t)q * H_ + c] = b;
}

// ---------------- W repack: fp32 k-major -> bf16 swizzled packets ----------
// Packet(e,cb,ks) = 64 rows x 8 granules(16B): physical granule p of row bn
// holds k = ks*64 + (p^(bn&7))*8 + j of col(bn). Contiguous 8KB per packet.
// W1 col map: col(bn) = half*I_ + cb*32 + grp*16 + sub (half=(bn>>4)&1, grp=bn>>5, sub=bn&15)
// W2 col map: col(bn) = hb*64 + bn.
// Reads are fully coalesced row segments; writes are contiguous 8KB packets.
__global__ __launch_bounds__(256) void transform_kernel(
    const float* __restrict__ W1, const float* __restrict__ W2,
    unsigned short* __restrict__ W1t, unsigned short* __restrict__ W2t)
{
    __shared__ float tile[64][65];
    const int t   = threadIdx.x;
    const int bid = blockIdx.x;

    if (bid < 4096) {                       // W1: e(16) x ks(16) x cb(16)
        const int cb = bid & 15, ks = (bid >> 4) & 15, e = bid >> 8;
        const float* __restrict__ W1e = W1 + (size_t)e * (H_ * 2 * I_);
        #pragma unroll
        for (int i = 0; i < 4; ++i) {
            int fi = i * 256 + t;           // 1024 float4 = 64 rows x 16
            int row = fi >> 4, c4 = fi & 15;
            const float* s = (c4 < 8)
                ? (W1e + (size_t)(ks * 64 + row) * (2 * I_) + cb * 32 + c4 * 4)
                : (W1e + (size_t)(ks * 64 + row) * (2 * I_) + I_ + cb * 32 + (c4 - 8) * 4);
            *(float4*)&tile[row][c4 * 4] = *(const float4*)s;
        }
        __syncthreads();
        unsigned short* __restrict__ dst =
            W1t + ((size_t)(e * 16 + cb) * 16 + ks) * 4096;
        #pragma unroll
        for (int s2 = 0; s2 < 2; ++s2) {
            int gidx = t * 2 + s2;          // 512 granules
            int bn = gidx >> 3, p = gidx & 7;
            int kl = (p ^ (bn & 7)) * 8;
            int c  = ((bn >> 4) & 1) * 32 + (bn >> 5) * 16 + (bn & 15);
            float v[8];
            #pragma unroll
            for (int j = 0; j < 8; ++j) v[j] = tile[kl + j][c];
            *(uint4*)&dst[(size_t)gidx * 8] = pack8(v);
        }
    } else {                                // W2: e(16) x ks(8) x hb(16)
        const int b2 = bid - 4096;
        const int hb = b2 & 15, ks = (b2 >> 4) & 7, e = b2 >> 7;
        const float* __restrict__ W2e = W2 + (size_t)e * (I_ * H_);
        #pragma unroll
        for (int i = 0; i < 4; ++i) {
            int fi = i * 256 + t;
            int row = fi >> 4, c4 = fi & 15;
            *(float4*)&tile[row][c4 * 4] =
                *(const float4*)(W2e + (size_t)(ks * 64 + row) * H_ + hb * 64 + c4 * 4);
        }
        __syncthreads();
        unsigned short* __restrict__ dst =
            W2t + ((size_t)(e * 16 + hb) * 8 + ks) * 4096;
        #pragma unroll
        for (int s2 = 0; s2 < 2; ++s2) {
            int gidx = t * 2 + s2;
            int bn = gidx >> 3, p = gidx & 7;
            int kl = (p ^ (bn & 7)) * 8;
            float v[8];
            #pragma unroll
            for (int j = 0; j < 8; ++j) v[j] = tile[kl + j][bn];
            *(uint4*)&dst[(size_t)gidx * 8] = pack8(v);
        }
    }
}

// ---------------- shared GEMM machinery ------------------------------------
// 4 waves (2x2), wave tile 64x32, block 128x64, BK=64.
// XOR-swizzled bf16 LDS: 16B granule g of row r holds k-granule g^(r&7).
#define MFMA_TILE(AS, BS)                                                              \
    _Pragma("unroll")                                                                  \
    for (int kkj = 0; kkj < 2; ++kkj) {                                                \
        const int j0 = kkj * 4;                                                        \
        bf16x8 af[4], bfr[2];                                                          \
        _Pragma("unroll")                                                              \
        for (int m = 0; m < 4; ++m)                                                    \
            af[m] = *(const bf16x8*)&AS[wm * 64 + m * 16 + lrow][((j0 + lk) ^ (lrow & 7)) * 8]; \
        _Pragma("unroll")                                                              \
        for (int n = 0; n < 2; ++n)                                                    \
            bfr[n] = *(const bf16x8*)&BS[wn * 32 + n * 16 + lrow][((j0 + lk) ^ (lrow & 7)) * 8]; \
        _Pragma("unroll")                                                              \
        for (int m = 0; m < 4; ++m)                                                    \
            _Pragma("unroll")                                                          \
            for (int n = 0; n < 2; ++n)                                                \
                acc[m][n] = __builtin_amdgcn_mfma_f32_16x16x32_bf16(af[m], bfr[n], acc[m][n], 0, 0, 0); \
    }

// A tile stage: 4 x gl_lds16 per wave (8 rows each), pre-swizzled source granules.
#define STAGE_A(BUF, KB)                                                               \
    _Pragma("unroll")                                                                  \
    for (int i = 0; i < 4; ++i) gl_lds16(asrc[i] + (KB), &As[BUF][w * 32 + i * 8][0]);

// B tile stage: 2 x gl_lds16 per wave, straight copy of packet bytes (the packet
// already IS the swizzled LDS image). bsrcB includes lane*8 + w*1024 (ushorts).
#define STAGE_B(BUF, KS)                                                               \
    _Pragma("unroll")                                                                  \
    for (int i = 0; i < 2; ++i)                                                        \
        gl_lds16(bsrcB + (size_t)(KS) * 4096 + i * 512,                                \
                 &Bs[BUF][0][0] + w * 1024 + i * 512);

// r4-proven 2-barrier skeleton: prefetch next tile, MFMA current, sync.
#define K_PIPE(NT)                                                                     \
    STAGE_A(0, 0)                                                                      \
    STAGE_B(0, 0)                                                                      \
    __syncthreads();                                                                   \
    int cur = 0;                                                                       \
    _Pragma("unroll")                                                                  \
    for (int kt = 0; kt < (NT); ++kt) {                                                \
        int nxt = cur ^ 1;                                                             \
        if (kt + 1 < (NT)) { STAGE_A(nxt, (kt + 1) * 64) STAGE_B(nxt, kt + 1) }        \
        __builtin_amdgcn_s_setprio(1);                                                 \
        MFMA_TILE(As[cur], Bs[cur])                                                    \
        __builtin_amdgcn_s_setprio(0);                                                 \
        __syncthreads();                                                               \
        cur = nxt;                                                                     \
    }

// ---------------- grouped GEMM1 + fused silu-gate --------------------------
// BM=128, BN=64 (32 gate + 32 up), K=H_=1024 (16 steps). Dense tile-mapped grid.
__global__ __launch_bounds__(256, 3) void gemm1_kernel(
    const unsigned short* __restrict__ Ag, const unsigned short* __restrict__ W1t,
    const int* __restrict__ offs, const int* __restrict__ tile_e,
    const int* __restrict__ tile_r, unsigned short* __restrict__ act)
{
    const int e = tile_e[blockIdx.y];
    if (e < 0) return;
    const int rbeg = offs[e], rend = offs[e + 1];
    const int ne   = rend - rbeg;
    const int row0 = tile_r[blockIdx.y];
    const int cb   = blockIdx.x;             // 0..15
    const int c0   = cb * 32;                // act col block

    __shared__ unsigned short As[2][128][64];   // 32 KB
    __shared__ unsigned short Bs[2][64][64];    // 16 KB

    const int tid  = threadIdx.x;
    const int lane = tid & 63;
    const int w    = tid >> 6;        // 0..3
    const int wm   = w >> 1, wn = w & 1;
    const int lrow = lane & 15;
    const int lk   = lane >> 4;

    // A sources: wave w stages rows [w*32, w*32+32), pre-swizzled granule
    const int r8 = lane >> 3, gr = lane & 7;
    const unsigned short* asrc[4];
    #pragma unroll
    for (int i = 0; i < 4; ++i) {
        int q = rbeg + row0 + w * 32 + i * 8 + r8;
        if (q > rend - 1) q = rend - 1;
        asrc[i] = Ag + (size_t)q * H_ + (gr ^ r8) * 8;
    }

    // B source: packet base for (e, cb); lane-linear copy
    const unsigned short* bsrcB =
        W1t + ((size_t)(e * 16 + cb) * 16) * 4096 + w * 1024 + lane * 8;

    f32x4 acc[4][2];
    #pragma unroll
    for (int m = 0; m < 4; ++m)
        #pragma unroll
        for (int n = 0; n < 2; ++n)
            acc[m][n] = f32x4{0.f, 0.f, 0.f, 0.f};

    K_PIPE(16)

    // epilogue: frag 0 = gate, frag 1 = up for act col c0 + wn*16 + lrow
    for (int m = 0; m < 4; ++m) {
        #pragma unroll
        for (int reg = 0; reg < 4; ++reg) {
            int rloc = wm * 64 + m * 16 + lk * 4 + reg;
            if (row0 + rloc < ne) {
                int q = rbeg + row0 + rloc;
                float g = acc[m][0][reg], u = acc[m][1][reg];
                float a = g / (1.f + __expf(-g)) * u;
                act[(size_t)q * I_ + c0 + wn * 16 + lrow] = f2bf(a);
            }
        }
    }
}

// ---------------- grouped GEMM2 + weighted atomic combine ------------------
// BM=128, BN=64, K=I_=512 (8 steps). Dense tile-mapped grid.
__global__ __launch_bounds__(256, 3) void gemm2_kernel(
    const unsigned short* __restrict__ Agact, const unsigned short* __restrict__ W2t,
    const int* __restrict__ offs, const int* __restrict__ tile_e,
    const int* __restrict__ tile_r, const int* __restrict__ pair_ts,
    const float* __restrict__ pair_w, float* __restrict__ out)
{
    const int e = tile_e[blockIdx.y];
    if (e < 0) return;
    const int rbeg = offs[e], rend = offs[e + 1];
    const int ne   = rend - rbeg;
    const int row0 = tile_r[blockIdx.y];
    const int hb   = blockIdx.x;             // 0..15
    const int c0   = hb * 64;

    __shared__ unsigned short As[2][128][64];
    __shared__ unsigned short Bs[2][64][64];

    const int tid  = threadIdx.x;
    const int lane = tid & 63;
    const int w    = tid >> 6;
    const int wm   = w >> 1, wn = w & 1;
    const int lrow = lane & 15;
    const int lk   = lane >> 4;

    const int r8 = lane >> 3, gr = lane & 7;
    const unsigned short* asrc[4];
    #pragma unroll
    for (int i = 0; i < 4; ++i) {
        int q = rbeg + row0 + w * 32 + i * 8 + r8;
        if (q > rend - 1) q = rend - 1;
        asrc[i] = Agact + (size_t)q * I_ + (gr ^ r8) * 8;
    }

    const unsigned short* bsrcB =
        W2t + ((size_t)(e * 16 + hb) * 8) * 4096 + w * 1024 + lane * 8;

    f32x4 acc[4][2];
    #pragma unroll
    for (int m = 0; m < 4; ++m)
        #pragma unroll
        for (int n = 0; n < 2; ++n)
            acc[m][n] = f32x4{0.f, 0.f, 0.f, 0.f};

    K_PIPE(8)

    for (int m = 0; m < 4; ++m) {
        #pragma unroll
        for (int reg = 0; reg < 4; ++reg) {
            int rloc = wm * 64 + m * 16 + lk * 4 + reg;
            if (row0 + rloc < ne) {
                int q   = rbeg + row0 + rloc;
                int t   = pair_ts[q] >> 1;
                float wt = pair_w[q];
                #pragma unroll
                for (int n = 0; n < 2; ++n) {
                    int cg = c0 + wn * 32 + n * 16 + lrow;
                    atomicAdd(&out[(size_t)t * H_ + cg], wt * acc[m][n][reg]);
                }
            }
        }
    }
}

extern "C" void kernel_launch(void* const* d_in, const int* in_sizes, int n_in,
                              void* d_out, int out_size, void* d_ws, size_t ws_size,
                              hipStream_t stream)
{
    const float* X  = (const float*)d_in[0];   // [T,H]
    const float* tw = (const float*)d_in[1];   // [T,K]
    const int*   ti = (const int*)d_in[2];     // [T,K]
    const float* W1 = (const float*)d_in[3];   // [E,H,2I]
    const float* W2 = (const float*)d_in[4];   // [E,I,H]
    float* out = (float*)d_out;                // [T,H] fp32

    char* ws = (char*)d_ws;
    int*   offs    = (int*)(ws);               // 17 ints
    int*   tile_e  = (int*)(ws + 128);
    int*   tile_r  = (int*)(ws + 320);
    int*   pair_ts = (int*)(ws + 1024);
    float* pair_w  = (float*)(ws + 1024 + NPAIR * 4);
    unsigned short* Ag  = (unsigned short*)(ws + (size_t)(1u << 16));            // 8 MiB
    unsigned short* act = (unsigned short*)(ws + (size_t)(1u << 16) + 8388608);  // 4 MiB
    unsigned short* W1t = (unsigned short*)(ws + (size_t)(1u << 16) + 12582912); // 32 MiB
    unsigned short* W2t = (unsigned short*)(ws + (size_t)(1u << 16) + 46137344); // 16 MiB

    hipMemsetAsync(d_out, 0, (size_t)out_size * sizeof(float), stream);

    route_kernel<<<1, 256, 0, stream>>>(tw, ti, offs, tile_e, tile_r, pair_ts, pair_w);

    gather_kernel<<<NPAIR, 256, 0, stream>>>(X, pair_ts, Ag);

    transform_kernel<<<6144, 256, 0, stream>>>(W1, W2, W1t, W2t);

    gemm1_kernel<<<dim3(16, MAXTILE), 256, 0, stream>>>(Ag, W1t, offs, tile_e, tile_r, act);

    gemm2_kernel<<<dim3(16, MAXTILE), 256, 0, stream>>>(act, W2t, offs, tile_e, tile_r, pair_ts, pair_w, out);
}

// Round 10
// 85.868 us; speedup vs baseline: 1.1608x; 1.0887x over previous
//
#include <hip/hip_runtime.h>

// MoE experts: transform W (fp32 -> bf16 swizzled packets, pipelined) -> route ->
// gather(bf16) -> grouped GEMM1+silu -> grouped GEMM2 (per-pair partials) -> combine.
// No memset, no atomics. GEMM staging is pure global_load_lds from L3-resident packets.
#define E_ 16
#define T_ 2048
#define H_ 1024
#define I_ 512
#define NPAIR 4096             // T*K token-expert pairs
#define BM 128
#define MAXTILE 48             // sum ceil(ne/BM) <= 32 + 16

typedef __bf16 bf16x8 __attribute__((ext_vector_type(8)));
typedef float  f32x4  __attribute__((ext_vector_type(4)));

static __device__ __forceinline__ unsigned short f2bf(float f) {
    __bf16 h = (__bf16)f;                       // RNE
    return __builtin_bit_cast(unsigned short, h);
}

static __device__ __forceinline__ uint4 pack8(const float* v) {
    union { unsigned short us[8]; uint4 u; } r;
    #pragma unroll
    for (int i = 0; i < 8; ++i) r.us[i] = f2bf(v[i]);
    return r.u;
}

// async global->LDS, 16B/lane; dest wave-uniform base + lane*16 (linear);
// source address is per-lane.
static __device__ __forceinline__ void gl_lds16(const void* g, void* l) {
    __builtin_amdgcn_global_load_lds(
        (const __attribute__((address_space(1))) unsigned int*)g,
        (__attribute__((address_space(3))) unsigned int*)l,
        16, 0, 0);
}

#define RAW_BARRIER_LGKM                                                \
    asm volatile("s_waitcnt lgkmcnt(0)" ::: "memory");                  \
    asm volatile("s_barrier" ::: "memory");

// ---------------- routing: stable counting sort + tile map + inverse -------
__global__ __launch_bounds__(256) void route_kernel(
    const float* __restrict__ tw, const int* __restrict__ ti,
    int* __restrict__ offs, int* __restrict__ tile_e, int* __restrict__ tile_r,
    int* __restrict__ pair_ts, float* __restrict__ pair_w, int* __restrict__ inv)
{
    __shared__ unsigned short hist[256][E_];
    __shared__ int ebase[E_];
    const int tid = threadIdx.x;

    int e_loc[16];
    unsigned short h[E_];
    for (int e = 0; e < E_; ++e) h[e] = 0;
    for (int i = 0; i < 16; ++i) {
        int p = tid * 16 + i;
        int e = ti[p];
        e_loc[i] = e;
        h[e]++;
    }
    for (int e = 0; e < E_; ++e) hist[tid][e] = h[e];
    __syncthreads();

    if (tid < E_) {
        int e = tid, run = 0;
        for (int t = 0; t < 256; ++t) {
            unsigned short c = hist[t][e];
            hist[t][e] = (unsigned short)run;
            run += c;
        }
        ebase[e] = run;
    }
    __syncthreads();
    if (tid == 0) {
        int run = 0, nt = 0;
        for (int e = 0; e < E_; ++e) {
            int c = ebase[e];
            offs[e] = run; ebase[e] = run;
            for (int r = 0; r < c; r += BM) { tile_e[nt] = e; tile_r[nt] = r; ++nt; }
            run += c;
        }
        offs[E_] = run;
        for (; nt < MAXTILE; ++nt) tile_e[nt] = -1;
    }
    __syncthreads();

    int cur[E_];
    for (int e = 0; e < E_; ++e) cur[e] = ebase[e] + hist[tid][e];
    for (int i = 0; i < 16; ++i) {
        int p = tid * 16 + i;
        int e = e_loc[i];
        int pos = cur[e]++;
        pair_ts[pos] = p;          // t = p>>1
        pair_w[pos]  = tw[p];
        inv[p]       = pos;
    }
}

// ---------------- gather: Ag[q][:] = bf16(X[token(q)][:]) ------------------
__global__ __launch_bounds__(256) void gather_kernel(
    const float* __restrict__ X, const int* __restrict__ pair_ts,
    unsigned short* __restrict__ Ag)
{
    const int q = blockIdx.x;
    const int t = pair_ts[q] >> 1;
    const int c = threadIdx.x * 4;
    const float4 x = *(const float4*)&X[(size_t)t * H_ + c];
    ushort4 b; b.x = f2bf(x.x); b.y = f2bf(x.y); b.z = f2bf(x.z); b.w = f2bf(x.w);
    *(ushort4*)&Ag[(size_t)q * H_ + c] = b;
}

// ---------------- W repack (pipelined): fp32 k-major -> bf16 packets -------
// Packet(e,colblk,ks) = 64 rows x 8 granules(16B): granule p of row bn holds
// k = ks*64 + (p^(bn&7))*8 + j of col(bn). Contiguous 8KB per packet.
// Each block processes 4 consecutive ks sub-tiles with a reg-staged double-buffer:
// loads for sub-tile s+1 are issued before packing sub-tile s; barriers drain
// LGKM only (global loads stay in flight across them).
__global__ __launch_bounds__(256, 4) void transform_kernel(
    const float* __restrict__ W1, const float* __restrict__ W2,
    unsigned short* __restrict__ W1t, unsigned short* __restrict__ W2t)
{
    __shared__ float tile[2][64][65];
    const int t  = threadIdx.x;
    const int c4 = t & 15, r0 = t >> 4;
    const int bid = blockIdx.x;
    float4 r[4];

    if (bid < 1024) {                       // W1: cb(16) x ksg(4) x e(16)
        const int cb = bid & 15, ksg = (bid >> 4) & 3, e = bid >> 6;
        const float* __restrict__ src = W1 + (size_t)e * (H_ * 2 * I_)
            + ((c4 < 8) ? (cb * 32 + c4 * 4) : (I_ + cb * 32 + (c4 - 8) * 4));
        unsigned short* __restrict__ dstb =
            W1t + ((size_t)(e * 16 + cb) * 16 + ksg * 4) * 4096;
        const int ks0 = ksg * 4;

        #pragma unroll
        for (int i = 0; i < 4; ++i)
            r[i] = *(const float4*)(src + (size_t)(ks0 * 64 + r0 + i * 16) * (2 * I_));
        #pragma unroll
        for (int i = 0; i < 4; ++i) *(float4*)&tile[0][r0 + i * 16][c4 * 4] = r[i];
        RAW_BARRIER_LGKM
        #pragma unroll
        for (int s = 0; s < 4; ++s) {
            if (s + 1 < 4) {
                #pragma unroll
                for (int i = 0; i < 4; ++i)
                    r[i] = *(const float4*)(src + (size_t)((ks0 + s + 1) * 64 + r0 + i * 16) * (2 * I_));
            }
            unsigned short* __restrict__ dst = dstb + s * 4096;
            #pragma unroll
            for (int s2 = 0; s2 < 2; ++s2) {
                int gidx = t * 2 + s2, bn = gidx >> 3, p = gidx & 7;
                int kl = (p ^ (bn & 7)) * 8;
                int c  = ((bn >> 4) & 1) * 32 + (bn >> 5) * 16 + (bn & 15);
                float v[8];
                #pragma unroll
                for (int j = 0; j < 8; ++j) v[j] = tile[s & 1][kl + j][c];
                *(uint4*)&dst[(size_t)gidx * 8] = pack8(v);
            }
            if (s + 1 < 4) {
                #pragma unroll
                for (int i = 0; i < 4; ++i)
                    *(float4*)&tile[(s + 1) & 1][r0 + i * 16][c4 * 4] = r[i];
                RAW_BARRIER_LGKM
            }
        }
    } else {                                // W2: hb(16) x ksg(2) x e(16)
        const int b2 = bid - 1024;
        const int hb = b2 & 15, ksg = (b2 >> 4) & 1, e = b2 >> 5;
        const float* __restrict__ src = W2 + (size_t)e * (I_ * H_) + hb * 64 + c4 * 4;
        unsigned short* __restrict__ dstb =
            W2t + ((size_t)(e * 16 + hb) * 8 + ksg * 4) * 4096;
        const int ks0 = ksg * 4;

        #pragma unroll
        for (int i = 0; i < 4; ++i)
            r[i] = *(const float4*)(src + (size_t)(ks0 * 64 + r0 + i * 16) * H_);
        #pragma unroll
        for (int i = 0; i < 4; ++i) *(float4*)&tile[0][r0 + i * 16][c4 * 4] = r[i];
        RAW_BARRIER_LGKM
        #pragma unroll
        for (int s = 0; s < 4; ++s) {
            if (s + 1 < 4) {
                #pragma unroll
                for (int i = 0; i < 4; ++i)
                    r[i] = *(const float4*)(src + (size_t)((ks0 + s + 1) * 64 + r0 + i * 16) * H_);
            }
            unsigned short* __restrict__ dst = dstb + s * 4096;
            #pragma unroll
            for (int s2 = 0; s2 < 2; ++s2) {
                int gidx = t * 2 + s2, bn = gidx >> 3, p = gidx & 7;
                int kl = (p ^ (bn & 7)) * 8;
                float v[8];
                #pragma unroll
                for (int j = 0; j < 8; ++j) v[j] = tile[s & 1][kl + j][bn];
                *(uint4*)&dst[(size_t)gidx * 8] = pack8(v);
            }
            if (s + 1 < 4) {
                #pragma unroll
                for (int i = 0; i < 4; ++i)
                    *(float4*)&tile[(s + 1) & 1][r0 + i * 16][c4 * 4] = r[i];
                RAW_BARRIER_LGKM
            }
        }
    }
}

// ---------------- shared GEMM machinery ------------------------------------
// 4 waves (2x2), wave tile 64x32, block 128x64, BK=64.
// XOR-swizzled bf16 LDS: 16B granule g of row r holds k-granule g^(r&7).
#define MFMA_TILE(AS, BS)                                                              \
    _Pragma("unroll")                                                                  \
    for (int kkj = 0; kkj < 2; ++kkj) {                                                \
        const int j0 = kkj * 4;                                                        \
        bf16x8 af[4], bfr[2];                                                          \
        _Pragma("unroll")                                                              \
        for (int m = 0; m < 4; ++m)                                                    \
            af[m] = *(const bf16x8*)&AS[wm * 64 + m * 16 + lrow][((j0 + lk) ^ (lrow & 7)) * 8]; \
        _Pragma("unroll")                                                              \
        for (int n = 0; n < 2; ++n)                                                    \
            bfr[n] = *(const bf16x8*)&BS[wn * 32 + n * 16 + lrow][((j0 + lk) ^ (lrow & 7)) * 8]; \
        _Pragma("unroll")                                                              \
        for (int m = 0; m < 4; ++m)                                                    \
            _Pragma("unroll")                                                          \
            for (int n = 0; n < 2; ++n)                                                \
                acc[m][n] = __builtin_amdgcn_mfma_f32_16x16x32_bf16(af[m], bfr[n], acc[m][n], 0, 0, 0); \
    }

#define STAGE_A(BUF, KB)                                                               \
    _Pragma("unroll")                                                                  \
    for (int i = 0; i < 4; ++i) gl_lds16(asrc[i] + (KB), &As[BUF][w * 32 + i * 8][0]);

#define STAGE_B(BUF, KS)                                                               \
    _Pragma("unroll")                                                                  \
    for (int i = 0; i < 2; ++i)                                                        \
        gl_lds16(bsrcB + (size_t)(KS) * 4096 + i * 512,                                \
                 &Bs[BUF][0][0] + w * 1024 + i * 512);

#define K_PIPE(NT)                                                                     \
    STAGE_A(0, 0)                                                                      \
    STAGE_B(0, 0)                                                                      \
    __syncthreads();                                                                   \
    int cur = 0;                                                                       \
    _Pragma("unroll")                                                                  \
    for (int kt = 0; kt < (NT); ++kt) {                                                \
        int nxt = cur ^ 1;                                                             \
        if (kt + 1 < (NT)) { STAGE_A(nxt, (kt + 1) * 64) STAGE_B(nxt, kt + 1) }        \
        __builtin_amdgcn_s_setprio(1);                                                 \
        MFMA_TILE(As[cur], Bs[cur])                                                    \
        __builtin_amdgcn_s_setprio(0);                                                 \
        __syncthreads();                                                               \
        cur = nxt;                                                                     \
    }

// ---------------- grouped GEMM1 + fused silu-gate --------------------------
__global__ __launch_bounds__(256, 3) void gemm1_kernel(
    const unsigned short* __restrict__ Ag, const unsigned short* __restrict__ W1t,
    const int* __restrict__ offs, const int* __restrict__ tile_e,
    const int* __restrict__ tile_r, unsigned short* __restrict__ act)
{
    const int e = tile_e[blockIdx.y];
    if (e < 0) return;
    const int rbeg = offs[e], rend = offs[e + 1];
    const int ne   = rend - rbeg;
    const int row0 = tile_r[blockIdx.y];
    const int cb   = blockIdx.x;             // 0..15
    const int c0   = cb * 32;                // act col block

    __shared__ unsigned short As[2][128][64];   // 32 KB
    __shared__ unsigned short Bs[2][64][64];    // 16 KB

    const int tid  = threadIdx.x;
    const int lane = tid & 63;
    const int w    = tid >> 6;        // 0..3
    const int wm   = w >> 1, wn = w & 1;
    const int lrow = lane & 15;
    const int lk   = lane >> 4;

    const int r8 = lane >> 3, gr = lane & 7;
    const unsigned short* asrc[4];
    #pragma unroll
    for (int i = 0; i < 4; ++i) {
        int q = rbeg + row0 + w * 32 + i * 8 + r8;
        if (q > rend - 1) q = rend - 1;
        asrc[i] = Ag + (size_t)q * H_ + (gr ^ r8) * 8;
    }

    const unsigned short* bsrcB =
        W1t + ((size_t)(e * 16 + cb) * 16) * 4096 + w * 1024 + lane * 8;

    f32x4 acc[4][2];
    #pragma unroll
    for (int m = 0; m < 4; ++m)
        #pragma unroll
        for (int n = 0; n < 2; ++n)
            acc[m][n] = f32x4{0.f, 0.f, 0.f, 0.f};

    K_PIPE(16)

    for (int m = 0; m < 4; ++m) {
        #pragma unroll
        for (int reg = 0; reg < 4; ++reg) {
            int rloc = wm * 64 + m * 16 + lk * 4 + reg;
            if (row0 + rloc < ne) {
                int q = rbeg + row0 + rloc;
                float g = acc[m][0][reg], u = acc[m][1][reg];
                float a = g / (1.f + __expf(-g)) * u;
                act[(size_t)q * I_ + c0 + wn * 16 + lrow] = f2bf(a);
            }
        }
    }
}

// ---------------- grouped GEMM2 -> per-pair partials (no atomics) ----------
__global__ __launch_bounds__(256, 3) void gemm2_kernel(
    const unsigned short* __restrict__ Agact, const unsigned short* __restrict__ W2t,
    const int* __restrict__ offs, const int* __restrict__ tile_e,
    const int* __restrict__ tile_r, const float* __restrict__ pair_w,
    float* __restrict__ C2)
{
    const int e = tile_e[blockIdx.y];
    if (e < 0) return;
    const int rbeg = offs[e], rend = offs[e + 1];
    const int ne   = rend - rbeg;
    const int row0 = tile_r[blockIdx.y];
    const int hb   = blockIdx.x;             // 0..15
    const int c0   = hb * 64;

    __shared__ unsigned short As[2][128][64];
    __shared__ unsigned short Bs[2][64][64];

    const int tid  = threadIdx.x;
    const int lane = tid & 63;
    const int w    = tid >> 6;
    const int wm   = w >> 1, wn = w & 1;
    const int lrow = lane & 15;
    const int lk   = lane >> 4;

    const int r8 = lane >> 3, gr = lane & 7;
    const unsigned short* asrc[4];
    #pragma unroll
    for (int i = 0; i < 4; ++i) {
        int q = rbeg + row0 + w * 32 + i * 8 + r8;
        if (q > rend - 1) q = rend - 1;
        asrc[i] = Agact + (size_t)q * I_ + (gr ^ r8) * 8;
    }

    const unsigned short* bsrcB =
        W2t + ((size_t)(e * 16 + hb) * 8) * 4096 + w * 1024 + lane * 8;

    f32x4 acc[4][2];
    #pragma unroll
    for (int m = 0; m < 4; ++m)
        #pragma unroll
        for (int n = 0; n < 2; ++n)
            acc[m][n] = f32x4{0.f, 0.f, 0.f, 0.f};

    K_PIPE(8)

    for (int m = 0; m < 4; ++m) {
        #pragma unroll
        for (int reg = 0; reg < 4; ++reg) {
            int rloc = wm * 64 + m * 16 + lk * 4 + reg;
            if (row0 + rloc < ne) {
                int q   = rbeg + row0 + rloc;
                float wt = pair_w[q];
                #pragma unroll
                for (int n = 0; n < 2; ++n) {
                    int cg = c0 + wn * 32 + n * 16 + lrow;
                    C2[(size_t)q * H_ + cg] = wt * acc[m][n][reg];
                }
            }
        }
    }
}

// ---------------- combine: out[t] = C2[inv[2t]] + C2[inv[2t+1]] ------------
__global__ __launch_bounds__(256) void combine_kernel(
    const float* __restrict__ C2, const int* __restrict__ inv,
    float* __restrict__ out)
{
    const int t = blockIdx.x;
    const int c = threadIdx.x * 4;
    const int q0 = inv[2 * t], q1 = inv[2 * t + 1];
    const float4 a = *(const float4*)&C2[(size_t)q0 * H_ + c];
    const float4 b = *(const float4*)&C2[(size_t)q1 * H_ + c];
    float4 o;
    o.x = a.x + b.x; o.y = a.y + b.y; o.z = a.z + b.z; o.w = a.w + b.w;
    *(float4*)&out[(size_t)t * H_ + c] = o;
}

extern "C" void kernel_launch(void* const* d_in, const int* in_sizes, int n_in,
                              void* d_out, int out_size, void* d_ws, size_t ws_size,
                              hipStream_t stream)
{
    const float* X  = (const float*)d_in[0];   // [T,H]
    const float* tw = (const float*)d_in[1];   // [T,K]
    const int*   ti = (const int*)d_in[2];     // [T,K]
    const float* W1 = (const float*)d_in[3];   // [E,H,2I]
    const float* W2 = (const float*)d_in[4];   // [E,I,H]
    float* out = (float*)d_out;                // [T,H] fp32

    char* ws = (char*)d_ws;
    int*   offs    = (int*)(ws);               // 17 ints
    int*   tile_e  = (int*)(ws + 128);
    int*   tile_r  = (int*)(ws + 320);
    int*   pair_ts = (int*)(ws + 1024);
    float* pair_w  = (float*)(ws + 1024 + NPAIR * 4);
    int*   inv     = (int*)(ws + 1024 + NPAIR * 8);
    unsigned short* Ag  = (unsigned short*)(ws + (size_t)(1u << 16));            // 8 MiB
    unsigned short* act = (unsigned short*)(ws + (size_t)(1u << 16) + 8388608);  // 4 MiB
    unsigned short* W1t = (unsigned short*)(ws + (size_t)(1u << 16) + 12582912); // 32 MiB
    unsigned short* W2t = (unsigned short*)(ws + (size_t)(1u << 16) + 46137344); // 16 MiB
    float*          C2  = (float*)(ws + (size_t)(1u << 16) + 62914560);          // 16 MiB

    transform_kernel<<<1536, 256, 0, stream>>>(W1, W2, W1t, W2t);

    route_kernel<<<1, 256, 0, stream>>>(tw, ti, offs, tile_e, tile_r, pair_ts, pair_w, inv);

    gather_kernel<<<NPAIR, 256, 0, stream>>>(X, pair_ts, Ag);

    gemm1_kernel<<<dim3(16, MAXTILE), 256, 0, stream>>>(Ag, W1t, offs, tile_e, tile_r, act);

    gemm2_kernel<<<dim3(16, MAXTILE), 256, 0, stream>>>(act, W2t, offs, tile_e, tile_r, pair_w, C2);

    combine_kernel<<<T_, 256, 0, stream>>>(C2, inv, out);
}